// Round 2
// baseline (87.029 us; speedup 1.0000x reference)
//
#include <hip/hip_runtime.h>

#define L_RES 4096
#define EPSF 1e-8f
#define RPB 64          // residues per block

typedef float floatx4 __attribute__((ext_vector_type(4)));   // clang-native for nontemporal builtin

struct V3 { float x, y, z; };

__device__ __forceinline__ V3 v3sub(V3 a, V3 b) { return {a.x-b.x, a.y-b.y, a.z-b.z}; }
__device__ __forceinline__ V3 v3cross(V3 a, V3 b) {
    return {a.y*b.z - a.z*b.y, a.z*b.x - a.x*b.z, a.x*b.y - a.y*b.x};
}
__device__ __forceinline__ float v3dot(V3 a, V3 b) { return a.x*b.x + a.y*b.y + a.z*b.z; }

// Returns (sin(dihedral), cos(dihedral)) matching the reference:
//   angle = arccos(clip(dot(n1n,n2n))) ; dihedral = angle * sign(dot(n1n, v3))
//   sin(dihedral) = sign * sqrt(1 - c^2);  cos(dihedral) = c   (sign != 0)
//   sign == 0  ->  dihedral = 0  ->  sin = 0, cos = 1
__device__ __forceinline__ void dihedral_sc(V3 p1, V3 p2, V3 p3, V3 p4,
                                            float& s_out, float& c_out) {
    V3 v1 = v3sub(p2, p1);
    V3 v2 = v3sub(p3, p2);
    V3 v3 = v3sub(p4, p3);
    V3 n1 = v3cross(v1, v2);
    V3 n2 = v3cross(v2, v3);
    float sq1 = v3dot(n1, n1);
    float sq2 = v3dot(n2, n2);
    float nrm1 = (sq1 > 0.f) ? sqrtf(sq1) : 0.f;   // _safe_norm semantics
    float nrm2 = (sq2 > 0.f) ? sqrtf(sq2) : 0.f;
    float inv1 = 1.f / (nrm1 + EPSF);
    float inv2 = 1.f / (nrm2 + EPSF);
    float c = (n1.x*n2.x + n1.y*n2.y + n1.z*n2.z) * (inv1 * inv2);
    c = fminf(1.f, fmaxf(-1.f, c));
    float sg = (n1.x*v3.x + n1.y*v3.y + n1.z*v3.z) * inv1;  // sign(dot(n1n,v3)) == sign(this)
    float sgn = (sg > 0.f) ? 1.f : ((sg < 0.f) ? -1.f : 0.f);
    float s = sqrtf(fmaxf(0.f, (1.f - c) * (1.f + c)));
    s_out = sgn * s;
    c_out = (sg == 0.f) ? 1.f : c;   // sign==0 -> angle*sign==0 -> cos==1
}

// Block = 256 threads handles RPB=64 consecutive residues of one batch row.
// Phase 1 (wave-parallel): wave d (d=0,1,2) computes dihedral type d (phi/psi/omega)
//   for residue (t&63); wave 3 idles (its W loads are already in flight).
// Phase 2: thread t owns output dims [4*(t&15), +4); residue group rg = t>>4;
//   4 iterations of fully coalesced nontemporal float4 stores.
__global__ __launch_bounds__(256) void dihedral_enc_kernel(
        const float* __restrict__ coords,   // (B, L, 4, 3)
        const float* __restrict__ W,        // (64, 6) row-major
        const float* __restrict__ bias,     // (64,)
        float* __restrict__ out) {          // (B, L, 64)
    __shared__ float enc_s[RPB * 7];        // stride 7: conflict-free LDS

    const int t   = threadIdx.x;
    const int blk = blockIdx.x;
    const int b   = blk >> 6;               // 64 chunks of 64 residues per L=4096 row
    const int l0  = (blk & 63) << 6;        // first residue of this block

    // W rows + bias into registers early: latency hides under phase-1 math.
    const int d4 = (t & 15) << 2;
    float w[4][6], bb[4];
    #pragma unroll
    for (int j = 0; j < 4; ++j) {
        bb[j] = bias[d4 + j];
        #pragma unroll
        for (int k = 0; k < 6; ++k) w[j][k] = W[(d4 + j) * 6 + k];
    }

    const long rowf = (long)b * L_RES * 12;        // float offset of batch row
    const float4* c4 = (const float4*)coords;

    const int d = t >> 6;                   // wave-uniform dihedral type 0..3
    const int r = t & 63;                   // residue within block
    const int l = l0 + r;

    if (d < 3) {
        // own residue: floats 0..8 = N, CA, C (12 floats, 48B-aligned)
        const long ownf = rowf + (long)l * 12;
        float4 a0 = c4[(ownf >> 2) + 0];
        float4 a1 = c4[(ownf >> 2) + 1];
        float  a2x = coords[ownf + 8];
        V3 N  = {a0.x, a0.y, a0.z};
        V3 CA = {a0.w, a1.x, a1.y};
        V3 C  = {a1.z, a1.w, a2x};

        float s, c;
        if (d == 0) {
            // phi: C_prev, N, CA, C   (C_prev clamped at l=0)
            const int lp = (l == 0) ? 0 : (l - 1);
            const long pf = rowf + (long)lp * 12;
            float4 pv = c4[(pf >> 2) + 1];          // floats 4..7
            float  p8 = coords[pf + 8];
            V3 C_prev = {pv.z, pv.w, p8};
            dihedral_sc(C_prev, N, CA, C, s, c);
        } else if (d == 1) {
            // psi: N, CA, C, N_next   (N_next clamped at l=L-1)
            const int ln = (l == L_RES - 1) ? l : (l + 1);
            const long nf = rowf + (long)ln * 12;
            float4 q0 = c4[(nf >> 2) + 0];
            V3 N_next = {q0.x, q0.y, q0.z};
            dihedral_sc(N, CA, C, N_next, s, c);
        } else {
            // omega: CA, C, om3, om4  (om3/om4 = N[l+1], CA[l+1]; l=L-1 -> CA[l], CA[l])
            const bool is_last = (l == L_RES - 1);
            const int ln = is_last ? l : (l + 1);
            const long nf = rowf + (long)ln * 12;
            float4 q0 = c4[(nf >> 2) + 0];
            float4 q1 = c4[(nf >> 2) + 1];
            V3 om3 = is_last ? CA : V3{q0.x, q0.y, q0.z};
            V3 om4 = is_last ? CA : V3{q0.w, q1.x, q1.y};
            dihedral_sc(CA, C, om3, om4, s, c);
        }
        // encoded = [sin phi, sin psi, sin om, cos phi, cos psi, cos om]
        enc_s[r * 7 + d]     = s;
        enc_s[r * 7 + 3 + d] = c;
    }

    __syncthreads();

    // Phase 2: 4 iterations; 16-lane broadcast LDS reads (conflict-free),
    // fully coalesced nontemporal float4 stores (64 MB stream, never re-read).
    const int rg = t >> 4;                       // residue subgroup 0..15
    floatx4* outp = (floatx4*)out;
    const long ob4 = (long)blk * (RPB * 16);     // blk*64 residues * 64 dims / 4
    #pragma unroll
    for (int it = 0; it < 4; ++it) {
        const int rr = it * 16 + rg;
        const float* er = &enc_s[rr * 7];
        float e0 = er[0], e1 = er[1], e2 = er[2];
        float e3 = er[3], e4 = er[4], e5 = er[5];
        floatx4 o;
        o.x = fmaf(e0, w[0][0], fmaf(e1, w[0][1], fmaf(e2, w[0][2],
              fmaf(e3, w[0][3], fmaf(e4, w[0][4], fmaf(e5, w[0][5], bb[0]))))));
        o.y = fmaf(e0, w[1][0], fmaf(e1, w[1][1], fmaf(e2, w[1][2],
              fmaf(e3, w[1][3], fmaf(e4, w[1][4], fmaf(e5, w[1][5], bb[1]))))));
        o.z = fmaf(e0, w[2][0], fmaf(e1, w[2][1], fmaf(e2, w[2][2],
              fmaf(e3, w[2][3], fmaf(e4, w[2][4], fmaf(e5, w[2][5], bb[2]))))));
        o.w = fmaf(e0, w[3][0], fmaf(e1, w[3][1], fmaf(e2, w[3][2],
              fmaf(e3, w[3][3], fmaf(e4, w[3][4], fmaf(e5, w[3][5], bb[3]))))));
        __builtin_nontemporal_store(o, &outp[ob4 + it * 256 + t]);
    }
}

extern "C" void kernel_launch(void* const* d_in, const int* in_sizes, int n_in,
                              void* d_out, int out_size, void* d_ws, size_t ws_size,
                              hipStream_t stream) {
    const float* coords = (const float*)d_in[0];
    const float* W      = (const float*)d_in[1];
    const float* bias   = (const float*)d_in[2];
    float* out          = (float*)d_out;

    const int total_res = in_sizes[0] / 12;      // B * L
    const int blocks    = total_res / RPB;       // 4096 for B=64, L=4096
    dihedral_enc_kernel<<<blocks, 256, 0, stream>>>(coords, W, bias, out);
}

// Round 3
// 85.449 us; speedup vs baseline: 1.0185x; 1.0185x over previous
//
#include <hip/hip_runtime.h>

#define L_RES 4096
#define EPSF 1e-8f

typedef float floatx4 __attribute__((ext_vector_type(4)));   // clang-native for nontemporal builtin

struct V3 { float x, y, z; };

__device__ __forceinline__ V3 v3sub(V3 a, V3 b) { return {a.x-b.x, a.y-b.y, a.z-b.z}; }
__device__ __forceinline__ V3 v3cross(V3 a, V3 b) {
    return {a.y*b.z - a.z*b.y, a.z*b.x - a.x*b.z, a.x*b.y - a.y*b.x};
}
__device__ __forceinline__ float v3dot(V3 a, V3 b) { return a.x*b.x + a.y*b.y + a.z*b.z; }

// Returns (sin(dihedral), cos(dihedral)) matching the reference:
//   angle = arccos(clip(dot(n1n,n2n))) ; dihedral = angle * sign(dot(n1n, v3))
//   sin(dihedral) = sign * sqrt(1 - c^2);  cos(dihedral) = c   (sign != 0)
//   sign == 0  ->  dihedral = 0  ->  sin = 0, cos = 1
__device__ __forceinline__ void dihedral_sc(V3 p1, V3 p2, V3 p3, V3 p4,
                                            float& s_out, float& c_out) {
    V3 v1 = v3sub(p2, p1);
    V3 v2 = v3sub(p3, p2);
    V3 v3 = v3sub(p4, p3);
    V3 n1 = v3cross(v1, v2);
    V3 n2 = v3cross(v2, v3);
    float sq1 = v3dot(n1, n1);
    float sq2 = v3dot(n2, n2);
    float nrm1 = (sq1 > 0.f) ? sqrtf(sq1) : 0.f;   // _safe_norm semantics
    float nrm2 = (sq2 > 0.f) ? sqrtf(sq2) : 0.f;
    float inv1 = 1.f / (nrm1 + EPSF);
    float inv2 = 1.f / (nrm2 + EPSF);
    float c = (n1.x*n2.x + n1.y*n2.y + n1.z*n2.z) * (inv1 * inv2);
    c = fminf(1.f, fmaxf(-1.f, c));
    float sg = (n1.x*v3.x + n1.y*v3.y + n1.z*v3.z) * inv1;  // sign(dot(n1n,v3)) == sign(this)
    float sgn = (sg > 0.f) ? 1.f : ((sg < 0.f) ? -1.f : 0.f);
    float s = sqrtf(fmaxf(0.f, (1.f - c) * (1.f + c)));
    s_out = sgn * s;
    c_out = (sg == 0.f) ? 1.f : c;   // sign==0 -> angle*sign==0 -> cos==1
}

// Block = 256 threads handles 256 consecutive residues of one batch row.
// Phase 0: stage the block's coord window (258 residues, clamped; N/CA/C only)
//          into LDS ONCE — global coord traffic = ideal 12.7 MB, no redundancy.
// Phase 1: thread t computes its residue's 3 dihedrals entirely from LDS.
// Phase 2: thread t owns output dims [4*(t&15), +4); 16 coalesced nontemporal
//          float4 stores (proven pattern).
__global__ __launch_bounds__(256) void dihedral_enc_kernel(
        const float* __restrict__ coords,   // (B, L, 4, 3)
        const float* __restrict__ W,        // (64, 6) row-major
        const float* __restrict__ bias,     // (64,)
        float* __restrict__ out) {          // (B, L, 64)
    __shared__ float crd[258 * 9];          // entry j <-> residue clamp(l0-1+j); stride 9 = conflict-free
    __shared__ float enc_s[256 * 7];        // stride 7: conflict-free

    const int t   = threadIdx.x;
    const int blk = blockIdx.x;
    const int b   = blk >> 4;               // 16 chunks of 256 per L=4096 row
    const int l0  = (blk & 15) << 8;

    const long rowf = (long)b * L_RES * 12;
    const float4* c4 = (const float4*)coords;

    // Phase 0: stage. Entry j holds N,CA,C (9 floats) of residue clamp(l0-1+j, 0, L-1).
    for (int j = t; j < 258; j += 256) {
        int lc = l0 - 1 + j;
        lc = (lc < 0) ? 0 : ((lc >= L_RES) ? (L_RES - 1) : lc);
        const long f = rowf + (long)lc * 12;
        float4 a0 = c4[(f >> 2) + 0];       // floats 0..3
        float4 a1 = c4[(f >> 2) + 1];       // floats 4..7
        float  a8 = coords[f + 8];          // float 8
        float* e = &crd[j * 9];
        e[0] = a0.x; e[1] = a0.y; e[2] = a0.z; e[3] = a0.w;
        e[4] = a1.x; e[5] = a1.y; e[6] = a1.z; e[7] = a1.w;
        e[8] = a8;
    }
    __syncthreads();

    // Phase 1: dihedrals from LDS only.
    const int l = l0 + t;
    const float* ep = &crd[t * 9];          // residue clamp(l-1): need C = floats 6..8
    const float* eo = &crd[(t + 1) * 9];    // residue l
    const float* en = &crd[(t + 2) * 9];    // residue clamp(l+1): need N, CA
    V3 C_prev = {ep[6], ep[7], ep[8]};
    V3 N      = {eo[0], eo[1], eo[2]};
    V3 CA     = {eo[3], eo[4], eo[5]};
    V3 C      = {eo[6], eo[7], eo[8]};
    V3 N_next = {en[0], en[1], en[2]};
    const bool is_last = (l == L_RES - 1);
    V3 om3 = is_last ? CA : N_next;
    V3 om4 = is_last ? CA : V3{en[3], en[4], en[5]};

    float s_phi, c_phi, s_psi, c_psi, s_om, c_om;
    dihedral_sc(C_prev, N, CA, C,  s_phi, c_phi);
    dihedral_sc(N, CA, C, N_next,  s_psi, c_psi);
    dihedral_sc(CA, C, om3, om4,   s_om,  c_om);

    // encoded = [sin phi, sin psi, sin om, cos phi, cos psi, cos om]
    float* e = &enc_s[t * 7];
    e[0] = s_phi; e[1] = s_psi; e[2] = s_om;
    e[3] = c_phi; e[4] = c_psi; e[5] = c_om;

    // W/bias into registers here: global-load latency hides under the barrier.
    const int d4 = (t & 15) << 2;
    float w[4][6], bb[4];
    #pragma unroll
    for (int j = 0; j < 4; ++j) {
        bb[j] = bias[d4 + j];
        #pragma unroll
        for (int k = 0; k < 6; ++k) w[j][k] = W[(d4 + j) * 6 + k];
    }

    __syncthreads();

    // Phase 2: 16-lane broadcast LDS reads (conflict-free), fully coalesced
    // nontemporal float4 stores (64 MB stream, never re-read).
    const int rg = t >> 4;                       // residue subgroup 0..15
    floatx4* outp = (floatx4*)out;
    const long ob4 = (long)blk * 4096;           // blk*256 residues * 64 dims / 4
    #pragma unroll 4
    for (int it = 0; it < 16; ++it) {
        const int rr = it * 16 + rg;
        const float* er = &enc_s[rr * 7];
        float e0 = er[0], e1 = er[1], e2 = er[2];
        float e3 = er[3], e4 = er[4], e5 = er[5];
        floatx4 o;
        o.x = fmaf(e0, w[0][0], fmaf(e1, w[0][1], fmaf(e2, w[0][2],
              fmaf(e3, w[0][3], fmaf(e4, w[0][4], fmaf(e5, w[0][5], bb[0]))))));
        o.y = fmaf(e0, w[1][0], fmaf(e1, w[1][1], fmaf(e2, w[1][2],
              fmaf(e3, w[1][3], fmaf(e4, w[1][4], fmaf(e5, w[1][5], bb[1]))))));
        o.z = fmaf(e0, w[2][0], fmaf(e1, w[2][1], fmaf(e2, w[2][2],
              fmaf(e3, w[2][3], fmaf(e4, w[2][4], fmaf(e5, w[2][5], bb[2]))))));
        o.w = fmaf(e0, w[3][0], fmaf(e1, w[3][1], fmaf(e2, w[3][2],
              fmaf(e3, w[3][3], fmaf(e4, w[3][4], fmaf(e5, w[3][5], bb[3]))))));
        __builtin_nontemporal_store(o, &outp[ob4 + it * 256 + t]);
    }
}

extern "C" void kernel_launch(void* const* d_in, const int* in_sizes, int n_in,
                              void* d_out, int out_size, void* d_ws, size_t ws_size,
                              hipStream_t stream) {
    const float* coords = (const float*)d_in[0];
    const float* W      = (const float*)d_in[1];
    const float* bias   = (const float*)d_in[2];
    float* out          = (float*)d_out;

    const int total_res = in_sizes[0] / 12;      // B * L
    const int blocks    = total_res / 256;       // 1024 for B=64, L=4096
    dihedral_enc_kernel<<<blocks, 256, 0, stream>>>(coords, W, bias, out);
}